// Round 1
// baseline (332.829 us; speedup 1.0000x reference)
//
#include <hip/hip_runtime.h>
#include <math.h>

#define B 1024
#define T 512
#define S 48
#define SOS 47
#define NEGV -9999.0f

// ---------------------------------------------------------------------------
// Numerator: numer[b] = sum_t (feat[b,t,st[t]] + trans[st[t], st[t-1]]) * mask
// ---------------------------------------------------------------------------
__global__ __launch_bounds__(64) void crf_numer(const float* __restrict__ feat,
                                                const int* __restrict__ states,
                                                const float* __restrict__ mask,
                                                const float* __restrict__ trans,
                                                float* __restrict__ numer) {
    const int b = blockIdx.x;
    const int lane = threadIdx.x;
    const int* st_b = states + b * T;
    const float* f_b = feat + (size_t)b * T * S;
    const float* m_b = mask + b * T;
    float sum = 0.f;
#pragma unroll
    for (int k = 0; k < T / 64; ++k) {
        const int t = lane + k * 64;
        const int st = st_b[t];
        const int pv = (t == 0) ? SOS : st_b[t - 1];
        sum += (f_b[t * S + st] + trans[st * S + pv]) * m_b[t];
    }
#pragma unroll
    for (int off = 32; off > 0; off >>= 1)
        sum += __shfl_xor(sum, off, 64);
    if (lane == 0) numer[b] = sum;
}

// ---------------------------------------------------------------------------
// Denominator: forward algorithm in exp-space.
//   new_i = emis_i + M + log( sum_j exp(trans[i,j]) * exp(score_j - M) )
// One wave per batch row; lane i owns state i. expT row lives in 48 VGPRs.
// p broadcast through LDS (single-wave block: LDS ops are in-order per wave,
// no barrier needed -> emission prefetch stays in flight).
// M re-derived each step from max_j p_j observed during the dot (free).
// ---------------------------------------------------------------------------
__global__ __launch_bounds__(64) void crf_denom(const float* __restrict__ feat,
                                                const float* __restrict__ mask,
                                                const float* __restrict__ trans,
                                                const float* __restrict__ numer,
                                                float* __restrict__ out) {
    __shared__ __align__(16) float pbuf[2][S];
    const int b = blockIdx.x;
    const int lane = threadIdx.x;
    const int elane = (lane < S) ? lane : 0;   // clamp for safe OOB-free loads
    const float* f_b = feat + (size_t)b * T * S;
    const float* m_b = mask + b * T;

    // expT row for this lane (exp(-9999) underflows to exact 0 -> dead arcs)
    float expT[S];
    {
        const float* trow = trans + elane * S;
#pragma unroll
        for (int j = 0; j < S; ++j) {
            const float e = __expf(trow[j]);
            expT[j] = (lane < S) ? e : 0.f;
        }
    }

    float s = (lane == SOS) ? 0.f : ((lane < S) ? NEGV : -INFINITY);
    float M = 0.f;   // exact max of initial scores

    // emission prefetch ring, depth 4
    float ering[4];
#pragma unroll
    for (int k = 0; k < 4; ++k)
        ering[k] = f_b[k * S + elane];

#pragma unroll 1
    for (int t0 = 0; t0 < T; t0 += 4) {
#pragma unroll
        for (int k = 0; k < 4; ++k) {
            const int t = t0 + k;
            const float p = __expf(s - M);        // dead states -> exact 0
            if (lane < S) pbuf[k & 1][lane] = p;
            const float4* pb = (const float4*)pbuf[k & 1];
            float ax = 0.f, ay = 0.f, az = 0.f, aw = 0.f;
            float mx = 1e-30f, my = 1e-30f, mz = 1e-30f, mw = 1e-30f;
#pragma unroll
            for (int j4 = 0; j4 < S / 4; ++j4) {
                const float4 pv = pb[j4];         // same-addr LDS broadcast
                ax = fmaf(expT[4 * j4 + 0], pv.x, ax);
                ay = fmaf(expT[4 * j4 + 1], pv.y, ay);
                az = fmaf(expT[4 * j4 + 2], pv.z, az);
                aw = fmaf(expT[4 * j4 + 3], pv.w, aw);
                mx = fmaxf(mx, pv.x);
                my = fmaxf(my, pv.y);
                mz = fmaxf(mz, pv.z);
                mw = fmaxf(mw, pv.w);
            }
            const float dot = (ax + ay) + (az + aw);
            const float pmax = fmaxf(fmaxf(mx, my), fmaxf(mz, mw));
            const float ns = ering[k] + M + __logf(dot);  // dot==0 -> -inf, ok
            const float mk = m_b[t];
            s = (mk != 0.f) ? ns : s;             // SELECT, never blend (-inf*0)
            M = M + __logf(pmax);                 // = max_j old score, uniform
            const int tp = (t + 4) & (T - 1);     // wrap; tail loads unused t=0..3
            ering[k] = f_b[tp * S + elane];       // prefetch 4 steps ahead
        }
    }

    // final logsumexp over states (exact, once)
    float mv = s;
#pragma unroll
    for (int off = 32; off > 0; off >>= 1)
        mv = fmaxf(mv, __shfl_xor(mv, off, 64));
    float ex = __expf(s - mv);                    // -inf lanes -> 0
#pragma unroll
    for (int off = 32; off > 0; off >>= 1)
        ex += __shfl_xor(ex, off, 64);
    const float denom = mv + __logf(ex);
    if (lane == 0) out[b] = denom - numer[b];
}

extern "C" void kernel_launch(void* const* d_in, const int* in_sizes, int n_in,
                              void* d_out, int out_size, void* d_ws, size_t ws_size,
                              hipStream_t stream) {
    const float* feat   = (const float*)d_in[0];   // (B,T,S) f32
    const int*   states = (const int*)d_in[1];     // (B,T) i32
    const float* mask   = (const float*)d_in[2];   // (B,T) f32
    const float* trans  = (const float*)d_in[3];   // (S,S) f32
    float* out   = (float*)d_out;                  // (B,) f32
    float* numer = (float*)d_ws;                   // B floats scratch

    crf_numer<<<dim3(B), dim3(64), 0, stream>>>(feat, states, mask, trans, numer);
    crf_denom<<<dim3(B), dim3(64), 0, stream>>>(feat, mask, trans, numer, out);
}

// Round 2
// 302.488 us; speedup vs baseline: 1.1003x; 1.1003x over previous
//
#include <hip/hip_runtime.h>
#include <math.h>

#define B 1024
#define T 512
#define S 48
#define SOS 47

// readlane(v, 1): uniform broadcast of lane 1's value (SALU path, cheap)
__device__ __forceinline__ float rdlane1(float v) {
    return __int_as_float(__builtin_amdgcn_readlane(__float_as_int(v), 1));
}

// ---------------------------------------------------------------------------
// Fused CRF loss. One wave per batch row; lane i owns state i.
// Forward scan kept in EXP space: p_i = exp(s_i - M), M uniform scalar.
//   d_i  = sum_j expT[i][j] * p_j          (48x48 matvec, expT in VGPRs)
//   p'_i = (d_i / d_1) * exp(emis_i - emis_1)   [shift to s_1: always live]
//   M   += emis_1 + log(d_1)               (parallel non-critical chain)
// exp() runs on prefetched emissions BEFORE the dot; log() only feeds M.
// Critical chain per step: ds_read -> 12-dep FMA -> readlane -> rcp -> mul
// -> ds_write. Single-wave block: LDS ops in-order, no __syncthreads.
// __launch_bounds__(64,1): full VGPR budget -> expT[48] stays in registers.
// ---------------------------------------------------------------------------
__global__ __launch_bounds__(64, 1) void crf_fused(const float* __restrict__ feat,
                                                   const int* __restrict__ states,
                                                   const float* __restrict__ mask,
                                                   const float* __restrict__ trans,
                                                   float* __restrict__ out) {
    __shared__ __align__(16) float pbuf[2][64];
    const int b = blockIdx.x;
    const int lane = threadIdx.x;
    const int elane = (lane < S) ? lane : 0;    // clamp: lanes 48-63 shadow lane 0
    const float* f_b = feat + (size_t)b * T * S;
    const float* m_b = mask + b * T;
    const int* st_b = states + b * T;

    // ---- numerator gathers (latency overlaps expT setup below) ----
    float nsum = 0.f;
#pragma unroll
    for (int k2 = 0; k2 < T / 64; ++k2) {
        const int t = lane + k2 * 64;
        const int st = st_b[t];
        const int pv = (t == 0) ? SOS : st_b[t - 1];
        nsum += (f_b[t * S + st] + trans[st * S + pv]) * m_b[t];
    }

    // ---- expT row for this lane (48 VGPRs); exp(-9999) -> exact 0 ----
    float expT[S];
    {
        const float4* t4 = (const float4*)(trans + elane * S);
#pragma unroll
        for (int j4 = 0; j4 < S / 4; ++j4) {
            const float4 tv = t4[j4];
            expT[4 * j4 + 0] = (lane < S) ? __expf(tv.x) : 0.f;
            expT[4 * j4 + 1] = (lane < S) ? __expf(tv.y) : 0.f;
            expT[4 * j4 + 2] = (lane < S) ? __expf(tv.z) : 0.f;
            expT[4 * j4 + 3] = (lane < S) ? __expf(tv.w) : 0.f;
        }
    }

    // ---- scan state ----
    float p = (lane == SOS) ? 1.f : 0.f;   // exp(s_init - 0)
    float M = 0.f;
    pbuf[0][lane] = p;

    // prefetch rings, depth 8 (~8 steps ahead > HBM miss latency)
    float ering[8], mring[8];
#pragma unroll
    for (int k = 0; k < 8; ++k) {
        ering[k] = f_b[k * S + elane];
        mring[k] = m_b[k];
    }

#pragma unroll 1
    for (int tb = 0; tb < T / 8; ++tb) {
#pragma unroll
        for (int k = 0; k < 8; ++k) {
            const int t = tb * 8 + k;
            // off-chain: emission shift factor from prefetched value
            const float emis = ering[k];
            const float er = rdlane1(emis);
            const float E = __expf(emis - er);
            // dot d_i = expT[i] . p  (LDS same-address broadcast reads)
            const float4* pb = (const float4*)pbuf[k & 1];
            float ax = 0.f, ay = 0.f, az = 0.f, aw = 0.f;
#pragma unroll
            for (int j4 = 0; j4 < S / 4; ++j4) {
                const float4 pv4 = pb[j4];
                ax = fmaf(expT[4 * j4 + 0], pv4.x, ax);
                ay = fmaf(expT[4 * j4 + 1], pv4.y, ay);
                az = fmaf(expT[4 * j4 + 2], pv4.z, az);
                aw = fmaf(expT[4 * j4 + 3], pv4.w, aw);
            }
            const float d = (ax + ay) + (az + aw);
            const float dr = rdlane1(d);               // state 1: always > 0
            const float rd = __builtin_amdgcn_rcpf(dr);
            const float pn = (d * rd) * E;             // dead states: d=0 -> 0
            const bool live = (mring[k] != 0.f);
            p = live ? pn : p;                         // SELECT, never blend
            M = live ? (M + er + __logf(dr)) : M;      // parallel chain
            pbuf[(k + 1) & 1][lane] = p;
            // refill rings 8 steps ahead (wrap: tail loads t=0..7, unused)
            const int tp = (t + 8) & (T - 1);
            ering[k] = f_b[tp * S + elane];
            mring[k] = m_b[tp];
        }
    }

    // ---- epilogue: denom = M + log(sum_i p_i);  out = denom - numer ----
    float ps = p;                                      // lanes>=48 hold 0
#pragma unroll
    for (int off = 32; off > 0; off >>= 1) {
        ps += __shfl_xor(ps, off, 64);
        nsum += __shfl_xor(nsum, off, 64);
    }
    if (lane == 0) out[b] = M + __logf(ps) - nsum;
}

extern "C" void kernel_launch(void* const* d_in, const int* in_sizes, int n_in,
                              void* d_out, int out_size, void* d_ws, size_t ws_size,
                              hipStream_t stream) {
    const float* feat   = (const float*)d_in[0];   // (B,T,S) f32
    const int*   states = (const int*)d_in[1];     // (B,T) i32
    const float* mask   = (const float*)d_in[2];   // (B,T) f32
    const float* trans  = (const float*)d_in[3];   // (S,S) f32
    float* out = (float*)d_out;                    // (B,) f32

    crf_fused<<<dim3(B), dim3(64), 0, stream>>>(feat, states, mask, trans, out);
}

// Round 3
// 284.412 us; speedup vs baseline: 1.1702x; 1.0636x over previous
//
#include <hip/hip_runtime.h>
#include <math.h>

#define B 1024
#define T 512
#define S 48
#define SOS 47

// broadcast lane 1's value to all lanes
__device__ __forceinline__ float rdlane1(float v) {
    return __int_as_float(__builtin_amdgcn_readlane(__float_as_int(v), 1));
}

// ---------------------------------------------------------------------------
// Fused CRF loss. One wave per row; lane i owns state i; expT row in VGPRs.
// Scan kept in exp space with DELAYED normalization:
//   invariant  u_t = q * exp(M)   (exact; r_s == exp(-l_s) pending factor)
//   live step: q' = (expT q) * exp(emis - er) * r_s ;  M += er + l_s
//              then r_s = rcp(d1), l_s = log(d1)   [off critical chain]
// Critical chain/step: ds_read(bcast) -> FMA dot -> mul -> select -> ds_write.
// Emission/mask prefetch double-buffered per 8-step block so vmem waits only
// ever hit loads aged by a full block (~1800 cyc > 900 cyc HBM latency).
// amdgpu_waves_per_eu(1): full VGPR budget; occupancy is structurally 1
// wave/SIMD (1024 single-wave blocks on 1024 SIMDs), so nothing is lost.
// ---------------------------------------------------------------------------
__global__ __launch_bounds__(64, 1)
__attribute__((amdgpu_waves_per_eu(1)))
void crf_fused(const float* __restrict__ feat,
               const int* __restrict__ states,
               const float* __restrict__ mask,
               const float* __restrict__ trans,
               float* __restrict__ out) {
    __shared__ __align__(16) float pbuf[2][64];
    const int b = blockIdx.x;
    const int lane = threadIdx.x;
    const int elane = (lane < S) ? lane : 0;    // lanes 48-63 shadow lane 0
    const float* f_b = feat + (size_t)b * T * S;
    const float* m_b = mask + b * T;
    const int* st_b = states + b * T;

    // ---- numerator (latency overlaps expT setup) ----
    float nsum = 0.f;
#pragma unroll
    for (int k2 = 0; k2 < T / 64; ++k2) {
        const int t = lane + k2 * 64;
        const int st = st_b[t];
        const int pv = (t == 0) ? SOS : st_b[t - 1];
        nsum += (f_b[t * S + st] + trans[st * S + pv]) * m_b[t];
    }

    // ---- expT row for this lane; exp(-9999) underflows to exact 0 ----
    float expT[S];
    {
        const float4* t4 = (const float4*)(trans + elane * S);
#pragma unroll
        for (int j4 = 0; j4 < S / 4; ++j4) {
            const float4 tv = t4[j4];
            expT[4 * j4 + 0] = (lane < S) ? __expf(tv.x) : 0.f;
            expT[4 * j4 + 1] = (lane < S) ? __expf(tv.y) : 0.f;
            expT[4 * j4 + 2] = (lane < S) ? __expf(tv.z) : 0.f;
            expT[4 * j4 + 3] = (lane < S) ? __expf(tv.w) : 0.f;
        }
    }

    // ---- scan state ----
    float q = (lane == SOS) ? 1.f : 0.f;
    float M = 0.f;
    float r_s = 1.f, l_s = 0.f;      // pending normalizer: r_s == exp(-l_s)
    pbuf[0][lane] = q;

    // emission/mask double-buffered block rings (8 steps per block)
    float ering[2][8], mring[2][8];
#pragma unroll
    for (int k = 0; k < 8; ++k) {
        ering[0][k] = f_b[k * S + elane];
        mring[0][k] = m_b[k];
    }

#pragma unroll 2
    for (int tb = 0; tb < T / 8; ++tb) {
        const int pb = tb & 1;
        // issue next block's loads now; consumed a full block later
        const int tn = ((tb + 1) & (T / 8 - 1)) * 8;   // wrap: last refill unused
#pragma unroll
        for (int k = 0; k < 8; ++k) {
            ering[pb ^ 1][k] = f_b[(tn + k) * S + elane];
            mring[pb ^ 1][k] = m_b[tn + k];
        }
#pragma unroll
        for (int k = 0; k < 8; ++k) {
            // off-chain: per-lane factor from prefetched emission
            const float emis = ering[pb][k];
            const float er = rdlane1(emis);
            const float F = __expf(emis - er) * r_s;
            // chain: broadcast dot d_i = expT[i] . q
            const float4* qb = (const float4*)pbuf[k & 1];
            float ax = 0.f, ay = 0.f, az = 0.f, aw = 0.f;
#pragma unroll
            for (int j4 = 0; j4 < S / 4; ++j4) {
                const float4 pv4 = qb[j4];      // same-address LDS broadcast
                ax = fmaf(expT[4 * j4 + 0], pv4.x, ax);
                ay = fmaf(expT[4 * j4 + 1], pv4.y, ay);
                az = fmaf(expT[4 * j4 + 2], pv4.z, az);
                aw = fmaf(expT[4 * j4 + 3], pv4.w, aw);
            }
            const float d = (ax + ay) + (az + aw);
            const float qn = d * F;
            const bool live = (mring[pb][k] != 0.f);
            q = live ? qn : q;                  // SELECT, never blend
            pbuf[(k + 1) & 1][lane] = q;
            // off-chain: next normalizer + shift bookkeeping
            M = live ? (M + er + l_s) : M;      // uses OLD l_s, then update
            const float dr = rdlane1(d);        // lane1 dot: provably > 0
            const float nl = __logf(dr);
            const float nr = __builtin_amdgcn_rcpf(dr);
            r_s = live ? nr : r_s;
            l_s = live ? nl : l_s;
        }
    }

    // ---- epilogue: denom = M + log(sum_i q_i); out = denom - numer ----
    float ps = q;                               // lanes >= 48 hold 0
#pragma unroll
    for (int off = 32; off > 0; off >>= 1) {
        ps += __shfl_xor(ps, off, 64);
        nsum += __shfl_xor(nsum, off, 64);
    }
    if (lane == 0) out[b] = M + __logf(ps) - nsum;
}

extern "C" void kernel_launch(void* const* d_in, const int* in_sizes, int n_in,
                              void* d_out, int out_size, void* d_ws, size_t ws_size,
                              hipStream_t stream) {
    const float* feat   = (const float*)d_in[0];   // (B,T,S) f32
    const int*   states = (const int*)d_in[1];     // (B,T) i32
    const float* mask   = (const float*)d_in[2];   // (B,T) f32
    const float* trans  = (const float*)d_in[3];   // (S,S) f32
    float* out = (float*)d_out;                    // (B,) f32

    crf_fused<<<dim3(B), dim3(64), 0, stream>>>(feat, states, mask, trans, out);
}